// Round 1
// baseline (308.574 us; speedup 1.0000x reference)
//
#include <hip/hip_runtime.h>

#define NN 100000
#define NE 1600000
#define DIN 128
#define DOUT 32

// ---------------------------------------------------------------------------
// k1: indegree count over edge targets (self-loop added later as +1)
// ---------------------------------------------------------------------------
__global__ void deg_count_kernel(const int* __restrict__ col, int* __restrict__ deg) {
    int e = blockIdx.x * blockDim.x + threadIdx.x;
    if (e < NE) atomicAdd(&deg[col[e]], 1);
}

// ---------------------------------------------------------------------------
// k2: dis[i] = rsqrt(deg[i] + 1)   (+1 is the self-loop)
// ---------------------------------------------------------------------------
__global__ void dis_kernel(const int* __restrict__ deg, float* __restrict__ dis) {
    int i = blockIdx.x * blockDim.x + threadIdx.x;
    if (i < NN) dis[i] = rsqrtf((float)(deg[i] + 1));
}

// ---------------------------------------------------------------------------
// k3: xw = x @ W  (fused: out = dis^2 * xw + b, the self-loop message +
//     initialization of the poisoned d_out)
//     One thread per output element (n, d). W staged in LDS (16 KB).
// ---------------------------------------------------------------------------
__global__ void xw_init_kernel(const float* __restrict__ x,
                               const float* __restrict__ W,
                               const float* __restrict__ b,
                               const float* __restrict__ dis,
                               float* __restrict__ xw,
                               float* __restrict__ out) {
    __shared__ float Ws[DIN * DOUT];  // 16 KB
    for (int i = threadIdx.x; i < DIN * DOUT; i += blockDim.x) Ws[i] = W[i];
    __syncthreads();

    int idx = blockIdx.x * blockDim.x + threadIdx.x;
    if (idx >= NN * DOUT) return;
    int n = idx >> 5;       // /32
    int d = idx & (DOUT-1); // %32
    const float* xr = x + (long long)n * DIN;
    float acc = 0.f;
#pragma unroll
    for (int k = 0; k < DIN; ++k) acc += xr[k] * Ws[k * DOUT + d];
    xw[idx] = acc;
    float di = dis[n];
    out[idx] = di * di * acc + b[d];
}

// ---------------------------------------------------------------------------
// k4: edge scatter: out[c][d] += dis[r]*dis[c]*xw[r][d]
//     One thread per (edge, d) pair -> one atomic each.
// ---------------------------------------------------------------------------
__global__ void scatter_kernel(const int* __restrict__ row,
                               const int* __restrict__ col,
                               const float* __restrict__ dis,
                               const float* __restrict__ xw,
                               float* __restrict__ out) {
    long long idx = (long long)blockIdx.x * blockDim.x + threadIdx.x;
    if (idx >= (long long)NE * DOUT) return;
    int e = (int)(idx >> 5);
    int d = (int)(idx & (DOUT-1));
    int r = row[e];
    int c = col[e];
    float nrm = dis[r] * dis[c];
    atomicAdd(&out[c * DOUT + d], nrm * xw[r * DOUT + d]);
}

// ---------------------------------------------------------------------------
extern "C" void kernel_launch(void* const* d_in, const int* in_sizes, int n_in,
                              void* d_out, int out_size, void* d_ws, size_t ws_size,
                              hipStream_t stream) {
    const float* x  = (const float*)d_in[0];
    const int*   ei = (const int*)d_in[1];   // [2, NE] int32
    const float* W  = (const float*)d_in[2];
    const float* b  = (const float*)d_in[3];
    float* out = (float*)d_out;

    const int* row = ei;        // edge_index[0] = source
    const int* col = ei + NE;   // edge_index[1] = target

    // workspace layout (all 16B-aligned offsets)
    char* ws = (char*)d_ws;
    int*   deg = (int*)(ws);                 // 400,000 B
    float* dis = (float*)(ws + 400000);      // 400,000 B
    float* xw  = (float*)(ws + 800000);      // 12.8 MB

    // zero degree counts
    hipMemsetAsync(deg, 0, NN * sizeof(int), stream);

    // k1: count indegrees
    {
        int threads = 256;
        int blocks = (NE + threads - 1) / threads;
        deg_count_kernel<<<blocks, threads, 0, stream>>>(col, deg);
    }
    // k2: dis = rsqrt(deg+1)
    {
        int threads = 256;
        int blocks = (NN + threads - 1) / threads;
        dis_kernel<<<blocks, threads, 0, stream>>>(deg, dis);
    }
    // k3: xw = x@W, out = dis^2*xw + b
    {
        int threads = 256;
        long long total = (long long)NN * DOUT;
        int blocks = (int)((total + threads - 1) / threads);
        xw_init_kernel<<<blocks, threads, 0, stream>>>(x, W, b, dis, xw, out);
    }
    // k4: edge scatter with atomics
    {
        int threads = 256;
        long long total = (long long)NE * DOUT;
        int blocks = (int)((total + threads - 1) / threads);
        scatter_kernel<<<blocks, threads, 0, stream>>>(row, col, dis, xw, out);
    }
}